// Round 1
// baseline (696.430 us; speedup 1.0000x reference)
//
#include <hip/hip_runtime.h>

#define NU 50000
#define NP 50000
#define NN 100000
#define NE 600000
#define H  128
#define O  16

// ---------------------------------------------------------------- init / degree
__global__ void k_init(int* __restrict__ cnt, int* __restrict__ cursor, int n) {
    int i = blockIdx.x * blockDim.x + threadIdx.x;
    if (i < n) { cnt[i] = 0; cursor[i] = 0; }
}

__global__ void k_count(const int* __restrict__ dst, int* __restrict__ cnt, int E) {
    int e = blockIdx.x * blockDim.x + threadIdx.x;
    if (e < E) atomicAdd(&cnt[dst[e]], 1);
}

__global__ void k_dinv(const int* __restrict__ cnt, float* __restrict__ dinv, int n) {
    int i = blockIdx.x * blockDim.x + threadIdx.x;
    if (i < n) dinv[i] = rsqrtf((float)(cnt[i] + 1));   // +1 self-loop; deg>=1 always
}

// ---------------------------------------------------------------- exclusive scan (3-pass)
#define SCAN_TPB 256
#define SCAN_VPT 4
#define SCAN_CHUNK (SCAN_TPB * SCAN_VPT)   // 1024

__global__ void k_scan1(const int* __restrict__ in, int* __restrict__ out,
                        int* __restrict__ bsums, int n) {
    __shared__ int sh[SCAN_TPB];
    int t = threadIdx.x, b = blockIdx.x;
    int base = b * SCAN_CHUNK + t * SCAN_VPT;
    int v[SCAN_VPT]; int s = 0;
#pragma unroll
    for (int i = 0; i < SCAN_VPT; i++) {
        int idx = base + i;
        v[i] = (idx < n) ? in[idx] : 0;
        s += v[i];
    }
    sh[t] = s; __syncthreads();
    for (int off = 1; off < SCAN_TPB; off <<= 1) {
        int x = (t >= off) ? sh[t - off] : 0;
        __syncthreads();
        sh[t] += x;
        __syncthreads();
    }
    int run = (t > 0) ? sh[t - 1] : 0;          // exclusive prefix of this thread
    if (t == SCAN_TPB - 1) bsums[b] = sh[t];    // block total
#pragma unroll
    for (int i = 0; i < SCAN_VPT; i++) {
        int idx = base + i;
        if (idx < n) out[idx] = run;
        run += v[i];
    }
}

__global__ void k_scan2(int* __restrict__ bsums, int nb, int* __restrict__ total) {
    __shared__ int sh[128];
    int t = threadIdx.x;
    int v = (t < nb) ? bsums[t] : 0;
    sh[t] = v; __syncthreads();
    for (int off = 1; off < 128; off <<= 1) {
        int x = (t >= off) ? sh[t - off] : 0;
        __syncthreads();
        sh[t] += x;
        __syncthreads();
    }
    if (t < nb) bsums[t] = sh[t] - v;           // exclusive
    if (t == 127) *total = sh[127];
}

__global__ void k_scan3(int* __restrict__ out, const int* __restrict__ bsums, int n) {
    int idx = blockIdx.x * blockDim.x + threadIdx.x;
    if (idx < n) out[idx] += bsums[idx / SCAN_CHUNK];
}

// ---------------------------------------------------------------- CSR fill (counting sort by dst)
__global__ void k_fill(const int* __restrict__ src, const int* __restrict__ dst,
                       const int* __restrict__ offs, int* __restrict__ cursor,
                       const float* __restrict__ dinv,
                       int* __restrict__ esrc, float* __restrict__ enorm, int E) {
    int e = blockIdx.x * blockDim.x + threadIdx.x;
    if (e < E) {
        int s = src[e], d = dst[e];
        int p = offs[d] + atomicAdd(&cursor[d], 1);
        esrc[p]  = s;
        enorm[p] = dinv[s] * dinv[d];   // same for all 3 layers
    }
}

// ---------------------------------------------------------------- dense node-feature GEMM
// out[orow0+bm+m][j] = sum_k X[xrow0+bm+m][k] * W[k][j] (+ bias[j])
// 8 nodes per 128-thread block; X rows staged in LDS (broadcast reads, no conflicts).
template <int K, bool BIAS>
__global__ void k_xform(const float* __restrict__ X, const float* __restrict__ W,
                        const float* __restrict__ bias, float* __restrict__ out,
                        int xrow0, int orow0) {
    __shared__ float xs[8 * K];
    int j  = threadIdx.x;             // 0..127
    int bm = blockIdx.x * 8;
    // flat coalesced copy of 8 contiguous rows
    for (int idx = j; idx < 8 * K; idx += 128)
        xs[idx] = X[(xrow0 + bm) * K + idx];
    __syncthreads();

    float acc[8];
#pragma unroll
    for (int m = 0; m < 8; m++) acc[m] = BIAS ? bias[j] : 0.0f;

    for (int k = 0; k < K; k++) {
        float w = W[k * H + j];       // coalesced across j
#pragma unroll
        for (int m = 0; m < 8; m++)
            acc[m] = fmaf(xs[m * K + k], w, acc[m]);   // LDS broadcast
    }
#pragma unroll
    for (int m = 0; m < 8; m++)
        out[(orow0 + bm + m) * H + j] = acc[m];
}

// ---------------------------------------------------------------- CSR gather + bias + ReLU
__global__ void k_aggregate(const float* __restrict__ y, const int* __restrict__ offs,
                            const int* __restrict__ esrc, const float* __restrict__ enorm,
                            const float* __restrict__ dinv, const float* __restrict__ bias,
                            float* __restrict__ out) {
    int i = blockIdx.x;
    int j = threadIdx.x;              // 0..127
    float di  = dinv[i];
    float acc = y[i * H + j] * (di * di) + bias[j];    // self-loop + bias
    int e0 = offs[i], e1 = offs[i + 1];
    for (int e = e0; e < e1; e++)
        acc = fmaf(enorm[e], y[esrc[e] * H + j], acc); // coalesced 512B gather/edge
    out[i * H + j] = fmaxf(acc, 0.0f);
}

// ---------------------------------------------------------------- output GEMM [NN,128]@[128,16]+bo
__global__ void k_out(const float* __restrict__ X, const float* __restrict__ Wo,
                      const float* __restrict__ bo, float* __restrict__ out) {
    __shared__ float xs[16 * (H + 1)];   // +1 pad: kills 16-way bank conflict on xs[m][k]
    __shared__ float ws[H * O];
    int t  = threadIdx.x;                // 0..255
    int m0 = blockIdx.x * 16;
    for (int idx = t; idx < 16 * H; idx += 256) {
        int m = idx >> 7, k = idx & 127;
        xs[m * (H + 1) + k] = X[m0 * H + idx];
    }
    for (int idx = t; idx < H * O; idx += 256) ws[idx] = Wo[idx];
    __syncthreads();

    int m = t >> 4, o = t & 15;
    float acc = bo[o];
    for (int k = 0; k < H; k++)
        acc = fmaf(xs[m * (H + 1) + k], ws[k * O + o], acc);
    out[(m0 + m) * O + o] = acc;
}

// ---------------------------------------------------------------- launch
extern "C" void kernel_launch(void* const* d_in, const int* in_sizes, int n_in,
                              void* d_out, int out_size, void* d_ws, size_t ws_size,
                              hipStream_t stream) {
    const float* user = (const float*)d_in[0];
    const float* prod = (const float*)d_in[1];
    const int*   eidx = (const int*)  d_in[2];
    const int*   edst = eidx + NE;           // edge_index[1]
    const int*   esrc_in = eidx;             // edge_index[0]
    const float* Wu = (const float*)d_in[3];
    const float* bu = (const float*)d_in[4];
    const float* Wp = (const float*)d_in[5];
    const float* bp = (const float*)d_in[6];
    const float* W1 = (const float*)d_in[7];
    const float* b1 = (const float*)d_in[8];
    const float* W2 = (const float*)d_in[9];
    const float* b2 = (const float*)d_in[10];
    const float* W3 = (const float*)d_in[11];
    const float* b3 = (const float*)d_in[12];
    const float* Wo = (const float*)d_in[13];
    const float* bo = (const float*)d_in[14];
    float* out = (float*)d_out;

    char* ws = (char*)d_ws;
    size_t p = 0;
    auto alloc = [&](size_t bytes) -> void* {
        void* r = ws + p;
        p += (bytes + 255) & ~(size_t)255;
        return r;
    };
    float* xA    = (float*)alloc((size_t)NN * H * 4);
    float* xB    = (float*)alloc((size_t)NN * H * 4);
    int*   cnt   = (int*)  alloc((size_t)NN * 4);
    int*   cursor= (int*)  alloc((size_t)NN * 4);
    int*   offs  = (int*)  alloc((size_t)(NN + 1) * 4);
    float* dinv  = (float*)alloc((size_t)NN * 4);
    int*   esrc  = (int*)  alloc((size_t)NE * 4);
    float* enorm = (float*)alloc((size_t)NE * 4);
    int*   bsums = (int*)  alloc(128 * 4);

    const int NBLK = (NN + SCAN_CHUNK - 1) / SCAN_CHUNK;   // 98

    // graph structure (once per call, reused across 3 layers)
    k_init <<<(NN + 255) / 256, 256, 0, stream>>>(cnt, cursor, NN);
    k_count<<<(NE + 255) / 256, 256, 0, stream>>>(edst, cnt, NE);
    k_dinv <<<(NN + 255) / 256, 256, 0, stream>>>(cnt, dinv, NN);
    k_scan1<<<NBLK, SCAN_TPB, 0, stream>>>(cnt, offs, bsums, NN);
    k_scan2<<<1, 128, 0, stream>>>(bsums, NBLK, offs + NN);
    k_scan3<<<(NN + 255) / 256, 256, 0, stream>>>(offs, bsums, NN);
    k_fill <<<(NE + 255) / 256, 256, 0, stream>>>(esrc_in, edst, offs, cursor, dinv,
                                                  esrc, enorm, NE);

    // input feature transforms -> xA
    k_xform<64, true> <<<NU / 8, 128, 0, stream>>>(user, Wu, bu, xA, 0, 0);
    k_xform<100, true><<<NP / 8, 128, 0, stream>>>(prod, Wp, bp, xA, 0, NU);

    // layer 1
    k_xform<H, false><<<NN / 8, 128, 0, stream>>>(xA, W1, nullptr, xB, 0, 0);
    k_aggregate<<<NN, H, 0, stream>>>(xB, offs, esrc, enorm, dinv, b1, xA);
    // layer 2
    k_xform<H, false><<<NN / 8, 128, 0, stream>>>(xA, W2, nullptr, xB, 0, 0);
    k_aggregate<<<NN, H, 0, stream>>>(xB, offs, esrc, enorm, dinv, b2, xA);
    // layer 3
    k_xform<H, false><<<NN / 8, 128, 0, stream>>>(xA, W3, nullptr, xB, 0, 0);
    k_aggregate<<<NN, H, 0, stream>>>(xB, offs, esrc, enorm, dinv, b3, xA);

    // output head
    k_out<<<NN / 16, 256, 0, stream>>>(xA, Wo, bo, out);
}

// Round 2
// 608.521 us; speedup vs baseline: 1.1445x; 1.1445x over previous
//
#include <hip/hip_runtime.h>

#define NU 50000
#define NP 50000
#define NN 100000
#define NE 600000
#define H  128
#define O  16

// ---------------------------------------------------------------- init / degree
__global__ void k_init(int* __restrict__ cnt, int* __restrict__ cursor, int n) {
    int i = blockIdx.x * blockDim.x + threadIdx.x;
    if (i < n) { cnt[i] = 0; cursor[i] = 0; }
}

__global__ void k_count(const int* __restrict__ dst, int* __restrict__ cnt, int E) {
    int e = blockIdx.x * blockDim.x + threadIdx.x;
    if (e < E) atomicAdd(&cnt[dst[e]], 1);
}

__global__ void k_dinv(const int* __restrict__ cnt, float* __restrict__ dinv, int n) {
    int i = blockIdx.x * blockDim.x + threadIdx.x;
    if (i < n) dinv[i] = rsqrtf((float)(cnt[i] + 1));   // +1 self-loop; deg>=1 always
}

// ---------------------------------------------------------------- exclusive scan (3-pass)
#define SCAN_TPB 256
#define SCAN_VPT 4
#define SCAN_CHUNK (SCAN_TPB * SCAN_VPT)   // 1024

__global__ void k_scan1(const int* __restrict__ in, int* __restrict__ out,
                        int* __restrict__ bsums, int n) {
    __shared__ int sh[SCAN_TPB];
    int t = threadIdx.x, b = blockIdx.x;
    int base = b * SCAN_CHUNK + t * SCAN_VPT;
    int v[SCAN_VPT]; int s = 0;
#pragma unroll
    for (int i = 0; i < SCAN_VPT; i++) {
        int idx = base + i;
        v[i] = (idx < n) ? in[idx] : 0;
        s += v[i];
    }
    sh[t] = s; __syncthreads();
    for (int off = 1; off < SCAN_TPB; off <<= 1) {
        int x = (t >= off) ? sh[t - off] : 0;
        __syncthreads();
        sh[t] += x;
        __syncthreads();
    }
    int run = (t > 0) ? sh[t - 1] : 0;          // exclusive prefix of this thread
    if (t == SCAN_TPB - 1) bsums[b] = sh[t];    // block total
#pragma unroll
    for (int i = 0; i < SCAN_VPT; i++) {
        int idx = base + i;
        if (idx < n) out[idx] = run;
        run += v[i];
    }
}

__global__ void k_scan2(int* __restrict__ bsums, int nb, int* __restrict__ total) {
    __shared__ int sh[128];
    int t = threadIdx.x;
    int v = (t < nb) ? bsums[t] : 0;
    sh[t] = v; __syncthreads();
    for (int off = 1; off < 128; off <<= 1) {
        int x = (t >= off) ? sh[t - off] : 0;
        __syncthreads();
        sh[t] += x;
        __syncthreads();
    }
    if (t < nb) bsums[t] = sh[t] - v;           // exclusive
    if (t == 127) *total = sh[127];
}

__global__ void k_scan3(int* __restrict__ out, const int* __restrict__ bsums, int n) {
    int idx = blockIdx.x * blockDim.x + threadIdx.x;
    if (idx < n) out[idx] += bsums[idx / SCAN_CHUNK];
}

// ---------------------------------------------------------------- CSR fill (counting sort by dst)
// Packed edge record: .x = src node, .y = bitcast norm (dinv[s]*dinv[d]).
// One 8B load in the gather instead of two dependent 4B loads.
__global__ void k_fill(const int* __restrict__ src, const int* __restrict__ dst,
                       const int* __restrict__ offs, int* __restrict__ cursor,
                       const float* __restrict__ dinv,
                       int2* __restrict__ epack, int E) {
    int e = blockIdx.x * blockDim.x + threadIdx.x;
    if (e < E) {
        int s = src[e], d = dst[e];
        int p = offs[d] + atomicAdd(&cursor[d], 1);
        int2 r;
        r.x = s;
        r.y = __float_as_int(dinv[s] * dinv[d]);
        epack[p] = r;
    }
}

// ---------------------------------------------------------------- dense node-feature GEMM
// 16 rows per 128-thread block. X-tile staged TRANSPOSED in LDS: xs[k][m],
// m-dim padded 16->20 so float4 reads are 16B-aligned (20*4=80 ≡ 0 mod 16)
// and staging writes are only 8-way conflicted (stride 20, gcd(20,32)=4).
// Inner loop per k: 4x ds_read_b128 (broadcast) + 1 coalesced W load + 16 FMA.
template <int K, bool BIAS>
__global__ void k_xform(const float* __restrict__ X, const float* __restrict__ W,
                        const float* __restrict__ bias, float* __restrict__ out,
                        int xrow0, int orow0) {
    __shared__ __align__(16) float xs[K][20];
    int j  = threadIdx.x;             // 0..127 (output column)
    int bm = blockIdx.x * 16;
    for (int idx = j; idx < 16 * K; idx += 128) {
        int m = idx / K, k = idx - m * K;
        xs[k][m] = X[(size_t)(xrow0 + bm) * K + idx];
    }
    __syncthreads();

    float acc[16];
#pragma unroll
    for (int m = 0; m < 16; m++) acc[m] = BIAS ? bias[j] : 0.0f;

#pragma unroll 4
    for (int k = 0; k < K; k++) {
        float w = W[k * H + j];       // coalesced across j, L1/L2-hot
        float4 a0 = *(const float4*)&xs[k][0];
        float4 a1 = *(const float4*)&xs[k][4];
        float4 a2 = *(const float4*)&xs[k][8];
        float4 a3 = *(const float4*)&xs[k][12];
        acc[0]  = fmaf(a0.x, w, acc[0]);  acc[1]  = fmaf(a0.y, w, acc[1]);
        acc[2]  = fmaf(a0.z, w, acc[2]);  acc[3]  = fmaf(a0.w, w, acc[3]);
        acc[4]  = fmaf(a1.x, w, acc[4]);  acc[5]  = fmaf(a1.y, w, acc[5]);
        acc[6]  = fmaf(a1.z, w, acc[6]);  acc[7]  = fmaf(a1.w, w, acc[7]);
        acc[8]  = fmaf(a2.x, w, acc[8]);  acc[9]  = fmaf(a2.y, w, acc[9]);
        acc[10] = fmaf(a2.z, w, acc[10]); acc[11] = fmaf(a2.w, w, acc[11]);
        acc[12] = fmaf(a3.x, w, acc[12]); acc[13] = fmaf(a3.y, w, acc[13]);
        acc[14] = fmaf(a3.z, w, acc[14]); acc[15] = fmaf(a3.w, w, acc[15]);
    }
#pragma unroll
    for (int m = 0; m < 16; m++)
        out[(size_t)(orow0 + bm + m) * H + j] = acc[m];
}

// ---------------------------------------------------------------- CSR gather + bias + ReLU
// One node per 128-thread block; 4 edges in flight (32 lanes per edge, float4
// loads = 16B/lane). Per-group partials reduced through LDS in the epilogue.
__global__ void k_aggregate(const float* __restrict__ y, const int* __restrict__ offs,
                            const int2* __restrict__ epack,
                            const float* __restrict__ dinv, const float* __restrict__ bias,
                            float* __restrict__ out) {
    __shared__ float sh[4][128];
    int i = blockIdx.x;
    int t = threadIdx.x;              // 0..127
    int g = t >> 5, l = t & 31;       // edge-group, lane-in-group
    int e0 = offs[i], e1 = offs[i + 1];

    const float4* y4 = (const float4*)y;     // row stride = 32 float4
    float4 acc = make_float4(0.f, 0.f, 0.f, 0.f);
    for (int e = e0 + g; e < e1; e += 4) {
        int2 pk = epack[e];                  // one 8B load (src + norm)
        float w  = __int_as_float(pk.y);
        float4 v = y4[pk.x * 32 + l];        // 512B coalesced row gather
        acc.x = fmaf(w, v.x, acc.x);
        acc.y = fmaf(w, v.y, acc.y);
        acc.z = fmaf(w, v.z, acc.z);
        acc.w = fmaf(w, v.w, acc.w);
    }
    *(float4*)&sh[g][4 * l] = acc;
    __syncthreads();

    int j = t;                               // feature
    float di = dinv[i];
    float r = sh[0][j] + sh[1][j] + sh[2][j] + sh[3][j];
    r = fmaf(y[(size_t)i * H + j], di * di, r) + bias[j];   // self-loop + bias
    out[(size_t)i * H + j] = fmaxf(r, 0.0f);
}

// ---------------------------------------------------------------- output GEMM [NN,128]@[128,16]+bo
__global__ void k_out(const float* __restrict__ X, const float* __restrict__ Wo,
                      const float* __restrict__ bo, float* __restrict__ out) {
    __shared__ float xs[16 * (H + 1)];   // +1 pad: kills 16-way bank conflict on xs[m][k]
    __shared__ float ws[H * O];
    int t  = threadIdx.x;                // 0..255
    int m0 = blockIdx.x * 16;
    for (int idx = t; idx < 16 * H; idx += 256) {
        int m = idx >> 7, k = idx & 127;
        xs[m * (H + 1) + k] = X[m0 * H + idx];
    }
    for (int idx = t; idx < H * O; idx += 256) ws[idx] = Wo[idx];
    __syncthreads();

    int m = t >> 4, o = t & 15;
    float acc = bo[o];
    for (int k = 0; k < H; k++)
        acc = fmaf(xs[m * (H + 1) + k], ws[k * O + o], acc);
    out[(m0 + m) * O + o] = acc;
}

// ---------------------------------------------------------------- launch
extern "C" void kernel_launch(void* const* d_in, const int* in_sizes, int n_in,
                              void* d_out, int out_size, void* d_ws, size_t ws_size,
                              hipStream_t stream) {
    const float* user = (const float*)d_in[0];
    const float* prod = (const float*)d_in[1];
    const int*   eidx = (const int*)  d_in[2];
    const int*   edst = eidx + NE;           // edge_index[1]
    const int*   esrc_in = eidx;             // edge_index[0]
    const float* Wu = (const float*)d_in[3];
    const float* bu = (const float*)d_in[4];
    const float* Wp = (const float*)d_in[5];
    const float* bp = (const float*)d_in[6];
    const float* W1 = (const float*)d_in[7];
    const float* b1 = (const float*)d_in[8];
    const float* W2 = (const float*)d_in[9];
    const float* b2 = (const float*)d_in[10];
    const float* W3 = (const float*)d_in[11];
    const float* b3 = (const float*)d_in[12];
    const float* Wo = (const float*)d_in[13];
    const float* bo = (const float*)d_in[14];
    float* out = (float*)d_out;

    char* ws = (char*)d_ws;
    size_t p = 0;
    auto alloc = [&](size_t bytes) -> void* {
        void* r = ws + p;
        p += (bytes + 255) & ~(size_t)255;
        return r;
    };
    float* xA    = (float*)alloc((size_t)NN * H * 4);
    float* xB    = (float*)alloc((size_t)NN * H * 4);
    int*   cnt   = (int*)  alloc((size_t)NN * 4);
    int*   cursor= (int*)  alloc((size_t)NN * 4);
    int*   offs  = (int*)  alloc((size_t)(NN + 1) * 4);
    float* dinv  = (float*)alloc((size_t)NN * 4);
    int2*  epack = (int2*) alloc((size_t)NE * 8);
    int*   bsums = (int*)  alloc(128 * 4);

    const int NBLK = (NN + SCAN_CHUNK - 1) / SCAN_CHUNK;   // 98

    // graph structure (once per call, reused across 3 layers)
    k_init <<<(NN + 255) / 256, 256, 0, stream>>>(cnt, cursor, NN);
    k_count<<<(NE + 255) / 256, 256, 0, stream>>>(edst, cnt, NE);
    k_dinv <<<(NN + 255) / 256, 256, 0, stream>>>(cnt, dinv, NN);
    k_scan1<<<NBLK, SCAN_TPB, 0, stream>>>(cnt, offs, bsums, NN);
    k_scan2<<<1, 128, 0, stream>>>(bsums, NBLK, offs + NN);
    k_scan3<<<(NN + 255) / 256, 256, 0, stream>>>(offs, bsums, NN);
    k_fill <<<(NE + 255) / 256, 256, 0, stream>>>(esrc_in, edst, offs, cursor, dinv,
                                                  epack, NE);

    // input feature transforms -> xA
    k_xform<64, true> <<<NU / 16, 128, 0, stream>>>(user, Wu, bu, xA, 0, 0);
    k_xform<100, true><<<NP / 16, 128, 0, stream>>>(prod, Wp, bp, xA, 0, NU);

    // layer 1
    k_xform<H, false><<<NN / 16, 128, 0, stream>>>(xA, W1, nullptr, xB, 0, 0);
    k_aggregate<<<NN, 128, 0, stream>>>(xB, offs, epack, dinv, b1, xA);
    // layer 2
    k_xform<H, false><<<NN / 16, 128, 0, stream>>>(xA, W2, nullptr, xB, 0, 0);
    k_aggregate<<<NN, 128, 0, stream>>>(xB, offs, epack, dinv, b2, xA);
    // layer 3
    k_xform<H, false><<<NN / 16, 128, 0, stream>>>(xA, W3, nullptr, xB, 0, 0);
    k_aggregate<<<NN, 128, 0, stream>>>(xB, offs, epack, dinv, b3, xA);

    // output head
    k_out<<<NN / 16, 256, 0, stream>>>(xA, Wo, bo, out);
}

// Round 3
// 588.479 us; speedup vs baseline: 1.1834x; 1.0341x over previous
//
#include <hip/hip_runtime.h>

#define NU 50000
#define NP 50000
#define NN 100000
#define NE 600000
#define H  128
#define O  16

// ---------------------------------------------------------------- init / degree
__global__ void k_init(int* __restrict__ cnt, int* __restrict__ cursor, int n) {
    int i = blockIdx.x * blockDim.x + threadIdx.x;
    if (i < n) { cnt[i] = 0; cursor[i] = 0; }
}

__global__ void k_count(const int* __restrict__ dst, int* __restrict__ cnt, int E) {
    int e = blockIdx.x * blockDim.x + threadIdx.x;
    if (e < E) atomicAdd(&cnt[dst[e]], 1);
}

__global__ void k_dinv(const int* __restrict__ cnt, float* __restrict__ dinv, int n) {
    int i = blockIdx.x * blockDim.x + threadIdx.x;
    if (i < n) dinv[i] = rsqrtf((float)(cnt[i] + 1));   // +1 self-loop; deg>=1 always
}

// ---------------------------------------------------------------- exclusive scan (3-pass)
#define SCAN_TPB 256
#define SCAN_VPT 4
#define SCAN_CHUNK (SCAN_TPB * SCAN_VPT)   // 1024

__global__ void k_scan1(const int* __restrict__ in, int* __restrict__ out,
                        int* __restrict__ bsums, int n) {
    __shared__ int sh[SCAN_TPB];
    int t = threadIdx.x, b = blockIdx.x;
    int base = b * SCAN_CHUNK + t * SCAN_VPT;
    int v[SCAN_VPT]; int s = 0;
#pragma unroll
    for (int i = 0; i < SCAN_VPT; i++) {
        int idx = base + i;
        v[i] = (idx < n) ? in[idx] : 0;
        s += v[i];
    }
    sh[t] = s; __syncthreads();
    for (int off = 1; off < SCAN_TPB; off <<= 1) {
        int x = (t >= off) ? sh[t - off] : 0;
        __syncthreads();
        sh[t] += x;
        __syncthreads();
    }
    int run = (t > 0) ? sh[t - 1] : 0;          // exclusive prefix of this thread
    if (t == SCAN_TPB - 1) bsums[b] = sh[t];    // block total
#pragma unroll
    for (int i = 0; i < SCAN_VPT; i++) {
        int idx = base + i;
        if (idx < n) out[idx] = run;
        run += v[i];
    }
}

__global__ void k_scan2(int* __restrict__ bsums, int nb, int* __restrict__ total) {
    __shared__ int sh[128];
    int t = threadIdx.x;
    int v = (t < nb) ? bsums[t] : 0;
    sh[t] = v; __syncthreads();
    for (int off = 1; off < 128; off <<= 1) {
        int x = (t >= off) ? sh[t - off] : 0;
        __syncthreads();
        sh[t] += x;
        __syncthreads();
    }
    if (t < nb) bsums[t] = sh[t] - v;           // exclusive
    if (t == 127) *total = sh[127];
}

__global__ void k_scan3(int* __restrict__ out, const int* __restrict__ bsums, int n) {
    int idx = blockIdx.x * blockDim.x + threadIdx.x;
    if (idx < n) out[idx] += bsums[idx / SCAN_CHUNK];
}

// ---------------------------------------------------------------- CSR fill (counting sort by dst)
__global__ void k_fill(const int* __restrict__ src, const int* __restrict__ dst,
                       const int* __restrict__ offs, int* __restrict__ cursor,
                       const float* __restrict__ dinv,
                       int2* __restrict__ epack, int E) {
    int e = blockIdx.x * blockDim.x + threadIdx.x;
    if (e < E) {
        int s = src[e], d = dst[e];
        int p = offs[d] + atomicAdd(&cursor[d], 1);
        int2 r;
        r.x = s;
        r.y = __float_as_int(dinv[s] * dinv[d]);
        epack[p] = r;
    }
}

// ---------------------------------------------------------------- register-blocked GEMM
// C[M,128] = A[M,K] @ W[K,128] (+bias). 256 threads, 128x128 tile, BK=16.
// Thread (c = tid&15, r = tid>>4) computes 8 rows (r*8..) x 8 cols
// ({4c..4c+3} U {64+4c..64+4c+3}) -> 64 FMAs per 4 ds_read_b128 (16 FMA/LDS inst).
// As transposed [k][row] pad 132: frag reads conflict-free; Bs col-split: 2-way (free).
template <int K, bool BIAS>
__launch_bounds__(256)
__global__ void k_gemm(const float* __restrict__ A, const float* __restrict__ W,
                       const float* __restrict__ bias, float* __restrict__ Cout,
                       int M, int orow0) {
    __shared__ __align__(16) float As[16][132];
    __shared__ __align__(16) float Bs[16][128];

    const int tid = threadIdx.x;
    const int m0  = blockIdx.x * 128;
    const int c4  = (tid & 15) * 4;      // col frag base (and +64)
    const int r0  = (tid >> 4) * 8;      // row frag base

    // staging assignments
    const int a_row = tid >> 1;          // 0..127
    const int a_kk  = (tid & 1) * 8;     // 0 or 8
    const int b_kk  = tid >> 4;          // 0..15
    const int b_c   = (tid & 15) * 8;    // 0..120

    float acc[8][8];
    if (BIAS) {
        float4 blo = *(const float4*)&bias[c4];
        float4 bhi = *(const float4*)&bias[64 + c4];
#pragma unroll
        for (int i = 0; i < 8; i++) {
            acc[i][0] = blo.x; acc[i][1] = blo.y; acc[i][2] = blo.z; acc[i][3] = blo.w;
            acc[i][4] = bhi.x; acc[i][5] = bhi.y; acc[i][6] = bhi.z; acc[i][7] = bhi.w;
        }
    } else {
#pragma unroll
        for (int i = 0; i < 8; i++)
#pragma unroll
            for (int j = 0; j < 8; j++) acc[i][j] = 0.0f;
    }

    const int NCH = (K + 15) / 16;
    const int a_grow = m0 + a_row;

    for (int ch = 0; ch < NCH; ch++) {
        const int k0 = ch * 16;
        // ---- global loads (before barrier, overlap with prior compute)
        float av[8];
        if (a_grow < M && k0 + 16 <= K) {
            float4 x0 = *(const float4*)&A[(size_t)a_grow * K + k0 + a_kk];
            float4 x1 = *(const float4*)&A[(size_t)a_grow * K + k0 + a_kk + 4];
            av[0] = x0.x; av[1] = x0.y; av[2] = x0.z; av[3] = x0.w;
            av[4] = x1.x; av[5] = x1.y; av[6] = x1.z; av[7] = x1.w;
        } else {
#pragma unroll
            for (int i = 0; i < 8; i++) {
                int k = k0 + a_kk + i;
                av[i] = (a_grow < M && k < K) ? A[(size_t)a_grow * K + k] : 0.0f;
            }
        }
        float4 bv0, bv1;
        const int b_gk = k0 + b_kk;
        if (b_gk < K) {
            bv0 = *(const float4*)&W[(size_t)b_gk * H + b_c];
            bv1 = *(const float4*)&W[(size_t)b_gk * H + b_c + 4];
        } else {
            bv0 = make_float4(0.f, 0.f, 0.f, 0.f);
            bv1 = bv0;
        }

        __syncthreads();   // previous tile fully consumed
        // ---- LDS writes
#pragma unroll
        for (int i = 0; i < 8; i++) As[a_kk + i][a_row] = av[i];   // 2-way, free
        *(float4*)&Bs[b_kk][b_c]     = bv0;
        *(float4*)&Bs[b_kk][b_c + 4] = bv1;
        __syncthreads();

        // ---- inner product
#pragma unroll
        for (int kk = 0; kk < 16; kk++) {
            float4 a0 = *(const float4*)&As[kk][r0];
            float4 a1 = *(const float4*)&As[kk][r0 + 4];
            float4 b0 = *(const float4*)&Bs[kk][c4];
            float4 b1 = *(const float4*)&Bs[kk][64 + c4];
            float a[8] = {a0.x, a0.y, a0.z, a0.w, a1.x, a1.y, a1.z, a1.w};
            float b[8] = {b0.x, b0.y, b0.z, b0.w, b1.x, b1.y, b1.z, b1.w};
#pragma unroll
            for (int i = 0; i < 8; i++)
#pragma unroll
                for (int j = 0; j < 8; j++)
                    acc[i][j] = fmaf(a[i], b[j], acc[i][j]);
        }
    }

    // ---- epilogue
#pragma unroll
    for (int i = 0; i < 8; i++) {
        int grow = m0 + r0 + i;
        if (grow < M) {
            float4 o0 = make_float4(acc[i][0], acc[i][1], acc[i][2], acc[i][3]);
            float4 o1 = make_float4(acc[i][4], acc[i][5], acc[i][6], acc[i][7]);
            *(float4*)&Cout[(size_t)(orow0 + grow) * H + c4]      = o0;
            *(float4*)&Cout[(size_t)(orow0 + grow) * H + 64 + c4] = o1;
        }
    }
}

// ---------------------------------------------------------------- CSR gather + bias + ReLU
__global__ void k_aggregate(const float* __restrict__ y, const int* __restrict__ offs,
                            const int2* __restrict__ epack,
                            const float* __restrict__ dinv, const float* __restrict__ bias,
                            float* __restrict__ out) {
    __shared__ float sh[4][128];
    int i = blockIdx.x;
    int t = threadIdx.x;              // 0..127
    int g = t >> 5, l = t & 31;       // edge-group, lane-in-group
    int e0 = offs[i], e1 = offs[i + 1];

    const float4* y4 = (const float4*)y;     // row stride = 32 float4
    float4 acc = make_float4(0.f, 0.f, 0.f, 0.f);
    for (int e = e0 + g; e < e1; e += 4) {
        int2 pk = epack[e];                  // one 8B load (src + norm)
        float w  = __int_as_float(pk.y);
        float4 v = y4[pk.x * 32 + l];        // 512B coalesced row gather
        acc.x = fmaf(w, v.x, acc.x);
        acc.y = fmaf(w, v.y, acc.y);
        acc.z = fmaf(w, v.z, acc.z);
        acc.w = fmaf(w, v.w, acc.w);
    }
    *(float4*)&sh[g][4 * l] = acc;
    __syncthreads();

    int j = t;                               // feature
    float di = dinv[i];
    float r = sh[0][j] + sh[1][j] + sh[2][j] + sh[3][j];
    r = fmaf(y[(size_t)i * H + j], di * di, r) + bias[j];   // self-loop + bias
    out[(size_t)i * H + j] = fmaxf(r, 0.0f);
}

// ---------------------------------------------------------------- output GEMM [NN,128]@[128,16]+bo
__global__ void k_out(const float* __restrict__ X, const float* __restrict__ Wo,
                      const float* __restrict__ bo, float* __restrict__ out) {
    __shared__ float xs[16 * (H + 1)];   // +1 pad: kills 16-way bank conflict on xs[m][k]
    __shared__ float ws[H * O];
    int t  = threadIdx.x;                // 0..255
    int m0 = blockIdx.x * 16;
    for (int idx = t; idx < 16 * H; idx += 256) {
        int m = idx >> 7, k = idx & 127;
        xs[m * (H + 1) + k] = X[m0 * H + idx];
    }
    for (int idx = t; idx < H * O; idx += 256) ws[idx] = Wo[idx];
    __syncthreads();

    int m = t >> 4, o = t & 15;
    float acc = bo[o];
    for (int k = 0; k < H; k++)
        acc = fmaf(xs[m * (H + 1) + k], ws[k * O + o], acc);
    out[(m0 + m) * O + o] = acc;
}

// ---------------------------------------------------------------- launch
extern "C" void kernel_launch(void* const* d_in, const int* in_sizes, int n_in,
                              void* d_out, int out_size, void* d_ws, size_t ws_size,
                              hipStream_t stream) {
    const float* user = (const float*)d_in[0];
    const float* prod = (const float*)d_in[1];
    const int*   eidx = (const int*)  d_in[2];
    const int*   edst = eidx + NE;           // edge_index[1]
    const int*   esrc_in = eidx;             // edge_index[0]
    const float* Wu = (const float*)d_in[3];
    const float* bu = (const float*)d_in[4];
    const float* Wp = (const float*)d_in[5];
    const float* bp = (const float*)d_in[6];
    const float* W1 = (const float*)d_in[7];
    const float* b1 = (const float*)d_in[8];
    const float* W2 = (const float*)d_in[9];
    const float* b2 = (const float*)d_in[10];
    const float* W3 = (const float*)d_in[11];
    const float* b3 = (const float*)d_in[12];
    const float* Wo = (const float*)d_in[13];
    const float* bo = (const float*)d_in[14];
    float* out = (float*)d_out;

    char* ws = (char*)d_ws;
    size_t p = 0;
    auto alloc = [&](size_t bytes) -> void* {
        void* r = ws + p;
        p += (bytes + 255) & ~(size_t)255;
        return r;
    };
    float* xA    = (float*)alloc((size_t)NN * H * 4);
    float* xB    = (float*)alloc((size_t)NN * H * 4);
    int*   cnt   = (int*)  alloc((size_t)NN * 4);
    int*   cursor= (int*)  alloc((size_t)NN * 4);
    int*   offs  = (int*)  alloc((size_t)(NN + 1) * 4);
    float* dinv  = (float*)alloc((size_t)NN * 4);
    int2*  epack = (int2*) alloc((size_t)NE * 8);
    int*   bsums = (int*)  alloc(128 * 4);

    const int NBLK = (NN + SCAN_CHUNK - 1) / SCAN_CHUNK;   // 98

    // graph structure (once per call, reused across 3 layers)
    k_init <<<(NN + 255) / 256, 256, 0, stream>>>(cnt, cursor, NN);
    k_count<<<(NE + 255) / 256, 256, 0, stream>>>(edst, cnt, NE);
    k_dinv <<<(NN + 255) / 256, 256, 0, stream>>>(cnt, dinv, NN);
    k_scan1<<<NBLK, SCAN_TPB, 0, stream>>>(cnt, offs, bsums, NN);
    k_scan2<<<1, 128, 0, stream>>>(bsums, NBLK, offs + NN);
    k_scan3<<<(NN + 255) / 256, 256, 0, stream>>>(offs, bsums, NN);
    k_fill <<<(NE + 255) / 256, 256, 0, stream>>>(esrc_in, edst, offs, cursor, dinv,
                                                  epack, NE);

    // input feature transforms -> xA
    k_gemm<64, true>  <<<(NU + 127) / 128, 256, 0, stream>>>(user, Wu, bu, xA, NU, 0);
    k_gemm<100, true> <<<(NP + 127) / 128, 256, 0, stream>>>(prod, Wp, bp, xA, NP, NU);

    // layer 1
    k_gemm<H, false><<<(NN + 127) / 128, 256, 0, stream>>>(xA, W1, nullptr, xB, NN, 0);
    k_aggregate<<<NN, 128, 0, stream>>>(xB, offs, epack, dinv, b1, xA);
    // layer 2
    k_gemm<H, false><<<(NN + 127) / 128, 256, 0, stream>>>(xA, W2, nullptr, xB, NN, 0);
    k_aggregate<<<NN, 128, 0, stream>>>(xB, offs, epack, dinv, b2, xA);
    // layer 3
    k_gemm<H, false><<<(NN + 127) / 128, 256, 0, stream>>>(xA, W3, nullptr, xB, NN, 0);
    k_aggregate<<<NN, 128, 0, stream>>>(xB, offs, epack, dinv, b3, xA);

    // output head
    k_out<<<NN / 16, 256, 0, stream>>>(xA, Wo, bo, out);
}

// Round 4
// 577.034 us; speedup vs baseline: 1.2069x; 1.0198x over previous
//
#include <hip/hip_runtime.h>

#define NU 50000
#define NP 50000
#define NN 100000
#define NE 600000
#define H  128
#define O  16

// ---------------------------------------------------------------- init / degree
__global__ void k_init(int* __restrict__ cnt, int* __restrict__ cursor, int n) {
    int i = blockIdx.x * blockDim.x + threadIdx.x;
    if (i < n) { cnt[i] = 0; cursor[i] = 0; }
}

__global__ void k_count(const int* __restrict__ dst, int* __restrict__ cnt, int E) {
    int e = blockIdx.x * blockDim.x + threadIdx.x;
    if (e < E) atomicAdd(&cnt[dst[e]], 1);
}

__global__ void k_dinv(const int* __restrict__ cnt, float* __restrict__ dinv, int n) {
    int i = blockIdx.x * blockDim.x + threadIdx.x;
    if (i < n) dinv[i] = rsqrtf((float)(cnt[i] + 1));   // +1 self-loop; deg>=1 always
}

// ---------------------------------------------------------------- exclusive scan (3-pass)
#define SCAN_TPB 256
#define SCAN_VPT 4
#define SCAN_CHUNK (SCAN_TPB * SCAN_VPT)   // 1024

__global__ void k_scan1(const int* __restrict__ in, int* __restrict__ out,
                        int* __restrict__ bsums, int n) {
    __shared__ int sh[SCAN_TPB];
    int t = threadIdx.x, b = blockIdx.x;
    int base = b * SCAN_CHUNK + t * SCAN_VPT;
    int v[SCAN_VPT]; int s = 0;
#pragma unroll
    for (int i = 0; i < SCAN_VPT; i++) {
        int idx = base + i;
        v[i] = (idx < n) ? in[idx] : 0;
        s += v[i];
    }
    sh[t] = s; __syncthreads();
    for (int off = 1; off < SCAN_TPB; off <<= 1) {
        int x = (t >= off) ? sh[t - off] : 0;
        __syncthreads();
        sh[t] += x;
        __syncthreads();
    }
    int run = (t > 0) ? sh[t - 1] : 0;          // exclusive prefix of this thread
    if (t == SCAN_TPB - 1) bsums[b] = sh[t];    // block total
#pragma unroll
    for (int i = 0; i < SCAN_VPT; i++) {
        int idx = base + i;
        if (idx < n) out[idx] = run;
        run += v[i];
    }
}

__global__ void k_scan2(int* __restrict__ bsums, int nb, int* __restrict__ total) {
    __shared__ int sh[128];
    int t = threadIdx.x;
    int v = (t < nb) ? bsums[t] : 0;
    sh[t] = v; __syncthreads();
    for (int off = 1; off < 128; off <<= 1) {
        int x = (t >= off) ? sh[t - off] : 0;
        __syncthreads();
        sh[t] += x;
        __syncthreads();
    }
    if (t < nb) bsums[t] = sh[t] - v;           // exclusive
    if (t == 127) *total = sh[127];
}

__global__ void k_scan3(int* __restrict__ out, const int* __restrict__ bsums, int n) {
    int idx = blockIdx.x * blockDim.x + threadIdx.x;
    if (idx < n) out[idx] += bsums[idx / SCAN_CHUNK];
}

// ---------------------------------------------------------------- CSR fill (counting sort by dst)
__global__ void k_fill(const int* __restrict__ src, const int* __restrict__ dst,
                       const int* __restrict__ offs, int* __restrict__ cursor,
                       const float* __restrict__ dinv,
                       int2* __restrict__ epack, int E) {
    int e = blockIdx.x * blockDim.x + threadIdx.x;
    if (e < E) {
        int s = src[e], d = dst[e];
        int p = offs[d] + atomicAdd(&cursor[d], 1);
        int2 r;
        r.x = s;
        r.y = __float_as_int(dinv[s] * dinv[d]);
        epack[p] = r;
    }
}

// ---------------------------------------------------------------- register-blocked GEMM
// C[M,128] = A[M,K] @ W[K,128] (+bias). 256 threads, 128x128 tile, BK=16.
template <int K, bool BIAS>
__launch_bounds__(256)
__global__ void k_gemm(const float* __restrict__ A, const float* __restrict__ W,
                       const float* __restrict__ bias, float* __restrict__ Cout,
                       int M, int orow0) {
    __shared__ __align__(16) float As[16][132];
    __shared__ __align__(16) float Bs[16][128];

    const int tid = threadIdx.x;
    const int m0  = blockIdx.x * 128;
    const int c4  = (tid & 15) * 4;      // col frag base (and +64)
    const int r0  = (tid >> 4) * 8;      // row frag base

    // staging assignments
    const int a_row = tid >> 1;          // 0..127
    const int a_kk  = (tid & 1) * 8;     // 0 or 8
    const int b_kk  = tid >> 4;          // 0..15
    const int b_c   = (tid & 15) * 8;    // 0..120

    float acc[8][8];
    if (BIAS) {
        float4 blo = *(const float4*)&bias[c4];
        float4 bhi = *(const float4*)&bias[64 + c4];
#pragma unroll
        for (int i = 0; i < 8; i++) {
            acc[i][0] = blo.x; acc[i][1] = blo.y; acc[i][2] = blo.z; acc[i][3] = blo.w;
            acc[i][4] = bhi.x; acc[i][5] = bhi.y; acc[i][6] = bhi.z; acc[i][7] = bhi.w;
        }
    } else {
#pragma unroll
        for (int i = 0; i < 8; i++)
#pragma unroll
            for (int j = 0; j < 8; j++) acc[i][j] = 0.0f;
    }

    const int NCH = (K + 15) / 16;
    const int a_grow = m0 + a_row;

    for (int ch = 0; ch < NCH; ch++) {
        const int k0 = ch * 16;
        // ---- global loads (before barrier, overlap with prior compute)
        float av[8];
        if (a_grow < M && k0 + 16 <= K) {
            float4 x0 = *(const float4*)&A[(size_t)a_grow * K + k0 + a_kk];
            float4 x1 = *(const float4*)&A[(size_t)a_grow * K + k0 + a_kk + 4];
            av[0] = x0.x; av[1] = x0.y; av[2] = x0.z; av[3] = x0.w;
            av[4] = x1.x; av[5] = x1.y; av[6] = x1.z; av[7] = x1.w;
        } else {
#pragma unroll
            for (int i = 0; i < 8; i++) {
                int k = k0 + a_kk + i;
                av[i] = (a_grow < M && k < K) ? A[(size_t)a_grow * K + k] : 0.0f;
            }
        }
        float4 bv0, bv1;
        const int b_gk = k0 + b_kk;
        if (b_gk < K) {
            bv0 = *(const float4*)&W[(size_t)b_gk * H + b_c];
            bv1 = *(const float4*)&W[(size_t)b_gk * H + b_c + 4];
        } else {
            bv0 = make_float4(0.f, 0.f, 0.f, 0.f);
            bv1 = bv0;
        }

        __syncthreads();   // previous tile fully consumed
        // ---- LDS writes
#pragma unroll
        for (int i = 0; i < 8; i++) As[a_kk + i][a_row] = av[i];   // 2-way, free
        *(float4*)&Bs[b_kk][b_c]     = bv0;
        *(float4*)&Bs[b_kk][b_c + 4] = bv1;
        __syncthreads();

        // ---- inner product
#pragma unroll
        for (int kk = 0; kk < 16; kk++) {
            float4 a0 = *(const float4*)&As[kk][r0];
            float4 a1 = *(const float4*)&As[kk][r0 + 4];
            float4 b0 = *(const float4*)&Bs[kk][c4];
            float4 b1 = *(const float4*)&Bs[kk][64 + c4];
            float a[8] = {a0.x, a0.y, a0.z, a0.w, a1.x, a1.y, a1.z, a1.w};
            float b[8] = {b0.x, b0.y, b0.z, b0.w, b1.x, b1.y, b1.z, b1.w};
#pragma unroll
            for (int i = 0; i < 8; i++)
#pragma unroll
                for (int j = 0; j < 8; j++)
                    acc[i][j] = fmaf(a[i], b[j], acc[i][j]);
        }
    }

    // ---- epilogue
#pragma unroll
    for (int i = 0; i < 8; i++) {
        int grow = m0 + r0 + i;
        if (grow < M) {
            float4 o0 = make_float4(acc[i][0], acc[i][1], acc[i][2], acc[i][3]);
            float4 o1 = make_float4(acc[i][4], acc[i][5], acc[i][6], acc[i][7]);
            *(float4*)&Cout[(size_t)(orow0 + grow) * H + c4]      = o0;
            *(float4*)&Cout[(size_t)(orow0 + grow) * H + 64 + c4] = o1;
        }
    }
}

// ---------------------------------------------------------------- CSR gather + bias + ReLU
// One WAVE per node: 64 lanes x float2 = 512B row. All edge records for the
// node batch-loaded in ONE int2 vector load (lane l holds epack[e0+l]), then
// broadcast per-edge via v_readlane (wave-uniform loop index -> scalar pipe).
// Row gathers issue back-to-back with no interleaved dependent loads; no LDS,
// no barrier. 4 nodes per 256-thread block.
__launch_bounds__(256)
__global__ void k_aggregate(const float* __restrict__ y, const int* __restrict__ offs,
                            const int2* __restrict__ epack,
                            const float* __restrict__ dinv, const float* __restrict__ bias,
                            float* __restrict__ out) {
    const int node = blockIdx.x * 4 + (threadIdx.x >> 6);
    const int l    = threadIdx.x & 63;
    const int e0 = offs[node], e1 = offs[node + 1];
    const int deg = e1 - e0;

    const float2* y2 = (const float2*)y;      // row stride = 64 float2
    float2 acc = make_float2(0.f, 0.f);

    for (int base = 0; base < deg; base += 64) {
        const int m = min(64, deg - base);
        int2 pk = (l < m) ? epack[e0 + base + l] : make_int2(0, 0);
#pragma unroll 4
        for (int j = 0; j < m; j++) {
            int   s = __builtin_amdgcn_readlane(pk.x, j);         // uniform
            float w = __int_as_float(__builtin_amdgcn_readlane(pk.y, j));
            float2 v = y2[(size_t)s * 64 + l];                    // 512B row
            acc.x = fmaf(w, v.x, acc.x);
            acc.y = fmaf(w, v.y, acc.y);
        }
    }

    const float  di = dinv[node];
    const float2 sv = y2[(size_t)node * 64 + l];                  // self-loop
    const float2 bv = *(const float2*)&bias[2 * l];
    float rx = fmaf(sv.x, di * di, acc.x) + bv.x;
    float ry = fmaf(sv.y, di * di, acc.y) + bv.y;
    float2 o = make_float2(fmaxf(rx, 0.f), fmaxf(ry, 0.f));
    *((float2*)out + (size_t)node * 64 + l) = o;
}

// ---------------------------------------------------------------- output GEMM [NN,128]@[128,16]+bo
__global__ void k_out(const float* __restrict__ X, const float* __restrict__ Wo,
                      const float* __restrict__ bo, float* __restrict__ out) {
    __shared__ float xs[16 * (H + 1)];   // +1 pad: kills 16-way bank conflict on xs[m][k]
    __shared__ float ws[H * O];
    int t  = threadIdx.x;                // 0..255
    int m0 = blockIdx.x * 16;
    for (int idx = t; idx < 16 * H; idx += 256) {
        int m = idx >> 7, k = idx & 127;
        xs[m * (H + 1) + k] = X[m0 * H + idx];
    }
    for (int idx = t; idx < H * O; idx += 256) ws[idx] = Wo[idx];
    __syncthreads();

    int m = t >> 4, o = t & 15;
    float acc = bo[o];
    for (int k = 0; k < H; k++)
        acc = fmaf(xs[m * (H + 1) + k], ws[k * O + o], acc);
    out[(m0 + m) * O + o] = acc;
}

// ---------------------------------------------------------------- launch
extern "C" void kernel_launch(void* const* d_in, const int* in_sizes, int n_in,
                              void* d_out, int out_size, void* d_ws, size_t ws_size,
                              hipStream_t stream) {
    const float* user = (const float*)d_in[0];
    const float* prod = (const float*)d_in[1];
    const int*   eidx = (const int*)  d_in[2];
    const int*   edst = eidx + NE;           // edge_index[1]
    const int*   esrc_in = eidx;             // edge_index[0]
    const float* Wu = (const float*)d_in[3];
    const float* bu = (const float*)d_in[4];
    const float* Wp = (const float*)d_in[5];
    const float* bp = (const float*)d_in[6];
    const float* W1 = (const float*)d_in[7];
    const float* b1 = (const float*)d_in[8];
    const float* W2 = (const float*)d_in[9];
    const float* b2 = (const float*)d_in[10];
    const float* W3 = (const float*)d_in[11];
    const float* b3 = (const float*)d_in[12];
    const float* Wo = (const float*)d_in[13];
    const float* bo = (const float*)d_in[14];
    float* out = (float*)d_out;

    char* ws = (char*)d_ws;
    size_t p = 0;
    auto alloc = [&](size_t bytes) -> void* {
        void* r = ws + p;
        p += (bytes + 255) & ~(size_t)255;
        return r;
    };
    float* xA    = (float*)alloc((size_t)NN * H * 4);
    float* xB    = (float*)alloc((size_t)NN * H * 4);
    int*   cnt   = (int*)  alloc((size_t)NN * 4);
    int*   cursor= (int*)  alloc((size_t)NN * 4);
    int*   offs  = (int*)  alloc((size_t)(NN + 1) * 4);
    float* dinv  = (float*)alloc((size_t)NN * 4);
    int2*  epack = (int2*) alloc((size_t)NE * 8);
    int*   bsums = (int*)  alloc(128 * 4);

    const int NBLK = (NN + SCAN_CHUNK - 1) / SCAN_CHUNK;   // 98

    // graph structure (once per call, reused across 3 layers)
    k_init <<<(NN + 255) / 256, 256, 0, stream>>>(cnt, cursor, NN);
    k_count<<<(NE + 255) / 256, 256, 0, stream>>>(edst, cnt, NE);
    k_dinv <<<(NN + 255) / 256, 256, 0, stream>>>(cnt, dinv, NN);
    k_scan1<<<NBLK, SCAN_TPB, 0, stream>>>(cnt, offs, bsums, NN);
    k_scan2<<<1, 128, 0, stream>>>(bsums, NBLK, offs + NN);
    k_scan3<<<(NN + 255) / 256, 256, 0, stream>>>(offs, bsums, NN);
    k_fill <<<(NE + 255) / 256, 256, 0, stream>>>(esrc_in, edst, offs, cursor, dinv,
                                                  epack, NE);

    // input feature transforms -> xA
    k_gemm<64, true>  <<<(NU + 127) / 128, 256, 0, stream>>>(user, Wu, bu, xA, NU, 0);
    k_gemm<100, true> <<<(NP + 127) / 128, 256, 0, stream>>>(prod, Wp, bp, xA, NP, NU);

    // layer 1
    k_gemm<H, false><<<(NN + 127) / 128, 256, 0, stream>>>(xA, W1, nullptr, xB, NN, 0);
    k_aggregate<<<NN / 4, 256, 0, stream>>>(xB, offs, epack, dinv, b1, xA);
    // layer 2
    k_gemm<H, false><<<(NN + 127) / 128, 256, 0, stream>>>(xA, W2, nullptr, xB, NN, 0);
    k_aggregate<<<NN / 4, 256, 0, stream>>>(xB, offs, epack, dinv, b2, xA);
    // layer 3
    k_gemm<H, false><<<(NN + 127) / 128, 256, 0, stream>>>(xA, W3, nullptr, xB, NN, 0);
    k_aggregate<<<NN / 4, 256, 0, stream>>>(xB, offs, epack, dinv, b3, xA);

    // output head
    k_out<<<NN / 16, 256, 0, stream>>>(xA, Wo, bo, out);
}

// Round 5
// 574.869 us; speedup vs baseline: 1.2115x; 1.0038x over previous
//
#include <hip/hip_runtime.h>

#define NU 50000
#define NP 50000
#define NN 100000
#define NE 600000
#define H  128
#define O  16

// ---------------------------------------------------------------- init / degree
__global__ void k_init(int* __restrict__ cnt, int* __restrict__ cursor, int n) {
    int i = blockIdx.x * blockDim.x + threadIdx.x;
    if (i < n) { cnt[i] = 0; cursor[i] = 0; }
}

__global__ void k_count(const int* __restrict__ dst, int* __restrict__ cnt, int E) {
    int e = blockIdx.x * blockDim.x + threadIdx.x;
    if (e < E) atomicAdd(&cnt[dst[e]], 1);
}

__global__ void k_dinv(const int* __restrict__ cnt, float* __restrict__ dinv, int n) {
    int i = blockIdx.x * blockDim.x + threadIdx.x;
    if (i < n) dinv[i] = rsqrtf((float)(cnt[i] + 1));   // +1 self-loop; deg>=1 always
}

// ---------------------------------------------------------------- exclusive scan (3-pass)
#define SCAN_TPB 256
#define SCAN_VPT 4
#define SCAN_CHUNK (SCAN_TPB * SCAN_VPT)   // 1024

__global__ void k_scan1(const int* __restrict__ in, int* __restrict__ out,
                        int* __restrict__ bsums, int n) {
    __shared__ int sh[SCAN_TPB];
    int t = threadIdx.x, b = blockIdx.x;
    int base = b * SCAN_CHUNK + t * SCAN_VPT;
    int v[SCAN_VPT]; int s = 0;
#pragma unroll
    for (int i = 0; i < SCAN_VPT; i++) {
        int idx = base + i;
        v[i] = (idx < n) ? in[idx] : 0;
        s += v[i];
    }
    sh[t] = s; __syncthreads();
    for (int off = 1; off < SCAN_TPB; off <<= 1) {
        int x = (t >= off) ? sh[t - off] : 0;
        __syncthreads();
        sh[t] += x;
        __syncthreads();
    }
    int run = (t > 0) ? sh[t - 1] : 0;          // exclusive prefix of this thread
    if (t == SCAN_TPB - 1) bsums[b] = sh[t];    // block total
#pragma unroll
    for (int i = 0; i < SCAN_VPT; i++) {
        int idx = base + i;
        if (idx < n) out[idx] = run;
        run += v[i];
    }
}

__global__ void k_scan2(int* __restrict__ bsums, int nb, int* __restrict__ total) {
    __shared__ int sh[128];
    int t = threadIdx.x;
    int v = (t < nb) ? bsums[t] : 0;
    sh[t] = v; __syncthreads();
    for (int off = 1; off < 128; off <<= 1) {
        int x = (t >= off) ? sh[t - off] : 0;
        __syncthreads();
        sh[t] += x;
        __syncthreads();
    }
    if (t < nb) bsums[t] = sh[t] - v;           // exclusive
    if (t == 127) *total = sh[127];
}

__global__ void k_scan3(int* __restrict__ out, const int* __restrict__ bsums, int n) {
    int idx = blockIdx.x * blockDim.x + threadIdx.x;
    if (idx < n) out[idx] += bsums[idx / SCAN_CHUNK];
}

// ---------------------------------------------------------------- CSR fill (counting sort by dst)
__global__ void k_fill(const int* __restrict__ src, const int* __restrict__ dst,
                       const int* __restrict__ offs, int* __restrict__ cursor,
                       const float* __restrict__ dinv,
                       int2* __restrict__ epack, int E) {
    int e = blockIdx.x * blockDim.x + threadIdx.x;
    if (e < E) {
        int s = src[e], d = dst[e];
        int p = offs[d] + atomicAdd(&cursor[d], 1);
        int2 r;
        r.x = s;
        r.y = __float_as_int(dinv[s] * dinv[d]);
        epack[p] = r;
    }
}

// ---------------------------------------------------------------- GEMM v3
// C[M,128] = A[M,K] @ W[K,128] (+bias). 256 threads, 128x128 tile.
// K-chunk = 64 -> at most 2 chunks (vs 8): LDS = As[64][128] (transposed A) +
// Bs[64][128] = 64 KB exactly -> 2 blocks/CU, only 2-4 barriers per block.
// Chunk-1 global loads issue before chunk-0 compute (latency hidden).
// Frag reads: stride 128 ≡ 0 mod 32 banks, rows 32w..32w+31 per wave cover all
// 32 banks -> conflict-free; Bs staging writes remapped to 16-bank spread.
template <int K, bool BIAS>
__launch_bounds__(256, 2)
__global__ void k_gemm2(const float* __restrict__ A, const float* __restrict__ W,
                        const float* __restrict__ bias, float* __restrict__ Cout,
                        int M, int orow0) {
    __shared__ __align__(16) float As[64][128];
    __shared__ __align__(16) float Bs[64][128];

    const int tid = threadIdx.x;
    const int m0  = blockIdx.x * 128;
    const int c4  = (tid & 15) * 4;      // col frag base (and +64)
    const int r0  = (tid >> 4) * 8;      // row frag base

    // A staging: 2 threads per row, each 32 consecutive k
    const int a_lrow = tid >> 1;
    const int a_koff = (tid & 1) * 32;
    const int a_grow = m0 + a_lrow;
    // W staging: 4 threads per k-row, interleaved 16B chunks (16-bank spread)
    const int w_k  = tid >> 2;
    const int w_c0 = (tid & 3) * 4;

    float4 av[8], wv[8];

    auto load_chunk = [&](int k0) {
        if (a_grow < M) {
            if (k0 + a_koff + 32 <= K) {
                const float* p = &A[(size_t)a_grow * K + k0 + a_koff];
#pragma unroll
                for (int j = 0; j < 8; j++) av[j] = *(const float4*)(p + 4 * j);
            } else {
#pragma unroll
                for (int j = 0; j < 8; j++)
#pragma unroll
                    for (int i = 0; i < 4; i++) {
                        int k = k0 + a_koff + 4 * j + i;
                        ((float*)&av[j])[i] = (k < K) ? A[(size_t)a_grow * K + k] : 0.0f;
                    }
            }
        } else {
#pragma unroll
            for (int j = 0; j < 8; j++) av[j] = make_float4(0.f, 0.f, 0.f, 0.f);
        }
        if (k0 + w_k < K) {
            const float* p = &W[(size_t)(k0 + w_k) * H + w_c0];
#pragma unroll
            for (int j = 0; j < 8; j++) wv[j] = *(const float4*)(p + 16 * j);
        } else {
#pragma unroll
            for (int j = 0; j < 8; j++) wv[j] = make_float4(0.f, 0.f, 0.f, 0.f);
        }
    };
    auto store_chunk = [&]() {
#pragma unroll
        for (int j = 0; j < 8; j++) {
            As[a_koff + 4 * j + 0][a_lrow] = av[j].x;   // 2-way, free
            As[a_koff + 4 * j + 1][a_lrow] = av[j].y;
            As[a_koff + 4 * j + 2][a_lrow] = av[j].z;
            As[a_koff + 4 * j + 3][a_lrow] = av[j].w;
            *(float4*)&Bs[w_k][w_c0 + 16 * j] = wv[j];
        }
    };

    float acc[8][8];
    if (BIAS) {
        float4 blo = *(const float4*)&bias[c4];
        float4 bhi = *(const float4*)&bias[64 + c4];
#pragma unroll
        for (int i = 0; i < 8; i++) {
            acc[i][0] = blo.x; acc[i][1] = blo.y; acc[i][2] = blo.z; acc[i][3] = blo.w;
            acc[i][4] = bhi.x; acc[i][5] = bhi.y; acc[i][6] = bhi.z; acc[i][7] = bhi.w;
        }
    } else {
#pragma unroll
        for (int i = 0; i < 8; i++)
#pragma unroll
            for (int j = 0; j < 8; j++) acc[i][j] = 0.0f;
    }

    const int NCH = (K + 63) / 64;
    load_chunk(0);

    for (int ch = 0; ch < NCH; ch++) {
        __syncthreads();
        store_chunk();
        __syncthreads();
        if (ch + 1 < NCH) load_chunk((ch + 1) * 64);   // in flight during compute

#pragma unroll 4
        for (int kk = 0; kk < 64; kk++) {
            float4 a0 = *(const float4*)&As[kk][r0];
            float4 a1 = *(const float4*)&As[kk][r0 + 4];
            float4 b0 = *(const float4*)&Bs[kk][c4];
            float4 b1 = *(const float4*)&Bs[kk][64 + c4];
            float a[8] = {a0.x, a0.y, a0.z, a0.w, a1.x, a1.y, a1.z, a1.w};
            float b[8] = {b0.x, b0.y, b0.z, b0.w, b1.x, b1.y, b1.z, b1.w};
#pragma unroll
            for (int i = 0; i < 8; i++)
#pragma unroll
                for (int j = 0; j < 8; j++)
                    acc[i][j] = fmaf(a[i], b[j], acc[i][j]);
        }
    }

#pragma unroll
    for (int i = 0; i < 8; i++) {
        int grow = m0 + r0 + i;
        if (grow < M) {
            float4 o0 = make_float4(acc[i][0], acc[i][1], acc[i][2], acc[i][3]);
            float4 o1 = make_float4(acc[i][4], acc[i][5], acc[i][6], acc[i][7]);
            *(float4*)&Cout[(size_t)(orow0 + grow) * H + c4]      = o0;
            *(float4*)&Cout[(size_t)(orow0 + grow) * H + 64 + c4] = o1;
        }
    }
}

// ---------------------------------------------------------------- CSR gather + bias + ReLU
// One WAVE per node: 64 lanes x float2 = 512B row; edge records batch-loaded
// (one int2/lane) then broadcast via readlane; no LDS, no barrier.
__launch_bounds__(256)
__global__ void k_aggregate(const float* __restrict__ y, const int* __restrict__ offs,
                            const int2* __restrict__ epack,
                            const float* __restrict__ dinv, const float* __restrict__ bias,
                            float* __restrict__ out) {
    const int node = blockIdx.x * 4 + (threadIdx.x >> 6);
    const int l    = threadIdx.x & 63;
    const int e0 = offs[node], e1 = offs[node + 1];
    const int deg = e1 - e0;

    const float2* y2 = (const float2*)y;      // row stride = 64 float2
    float2 acc = make_float2(0.f, 0.f);

    for (int base = 0; base < deg; base += 64) {
        const int m = min(64, deg - base);
        int2 pk = (l < m) ? epack[e0 + base + l] : make_int2(0, 0);
#pragma unroll 4
        for (int j = 0; j < m; j++) {
            int   s = __builtin_amdgcn_readlane(pk.x, j);         // uniform
            float w = __int_as_float(__builtin_amdgcn_readlane(pk.y, j));
            float2 v = y2[(size_t)s * 64 + l];                    // 512B row
            acc.x = fmaf(w, v.x, acc.x);
            acc.y = fmaf(w, v.y, acc.y);
        }
    }

    const float  di = dinv[node];
    const float2 sv = y2[(size_t)node * 64 + l];                  // self-loop
    const float2 bv = *(const float2*)&bias[2 * l];
    float rx = fmaf(sv.x, di * di, acc.x) + bv.x;
    float ry = fmaf(sv.y, di * di, acc.y) + bv.y;
    float2 o = make_float2(fmaxf(rx, 0.f), fmaxf(ry, 0.f));
    *((float2*)out + (size_t)node * 64 + l) = o;
}

// ---------------------------------------------------------------- output GEMM [NN,128]@[128,16]
// Full X row-tile (128x128 = 64 KB) transposed in LDS, ONE barrier.
// Thread tile: 8 rows x 1 col; Wo (8 KB) read from global (L1 broadcast).
__launch_bounds__(256, 2)
__global__ void k_out2(const float* __restrict__ X, const float* __restrict__ Wo,
                       const float* __restrict__ bo, float* __restrict__ out, int M) {
    __shared__ float As[128][128];
    const int tid  = threadIdx.x;
    const int m0   = blockIdx.x * 128;
    const int lrow = tid >> 1;
    const int koff = (tid & 1) * 64;
    const int grow = m0 + lrow;

    if (grow < M) {
        const float* p = &X[(size_t)grow * H + koff];
#pragma unroll
        for (int j = 0; j < 16; j++) {
            float4 v = *(const float4*)(p + 4 * j);
            As[koff + 4 * j + 0][lrow] = v.x;
            As[koff + 4 * j + 1][lrow] = v.y;
            As[koff + 4 * j + 2][lrow] = v.z;
            As[koff + 4 * j + 3][lrow] = v.w;
        }
    } else {
#pragma unroll
        for (int j = 0; j < 64; j++) As[koff + j][lrow] = 0.0f;
    }
    __syncthreads();

    const int o  = tid & 15;
    const int r0 = (tid >> 4) * 8;
    float acc[8];
    float bias = bo[o];
#pragma unroll
    for (int i = 0; i < 8; i++) acc[i] = bias;

#pragma unroll 4
    for (int kk = 0; kk < H; kk++) {
        float w  = Wo[kk * O + o];                 // L1-hot broadcast
        float4 a0 = *(const float4*)&As[kk][r0];
        float4 a1 = *(const float4*)&As[kk][r0 + 4];
        acc[0] = fmaf(a0.x, w, acc[0]); acc[1] = fmaf(a0.y, w, acc[1]);
        acc[2] = fmaf(a0.z, w, acc[2]); acc[3] = fmaf(a0.w, w, acc[3]);
        acc[4] = fmaf(a1.x, w, acc[4]); acc[5] = fmaf(a1.y, w, acc[5]);
        acc[6] = fmaf(a1.z, w, acc[6]); acc[7] = fmaf(a1.w, w, acc[7]);
    }
#pragma unroll
    for (int i = 0; i < 8; i++) {
        int r = m0 + r0 + i;
        if (r < M) out[(size_t)r * O + o] = acc[i];
    }
}

// ---------------------------------------------------------------- launch
extern "C" void kernel_launch(void* const* d_in, const int* in_sizes, int n_in,
                              void* d_out, int out_size, void* d_ws, size_t ws_size,
                              hipStream_t stream) {
    const float* user = (const float*)d_in[0];
    const float* prod = (const float*)d_in[1];
    const int*   eidx = (const int*)  d_in[2];
    const int*   edst = eidx + NE;           // edge_index[1]
    const int*   esrc_in = eidx;             // edge_index[0]
    const float* Wu = (const float*)d_in[3];
    const float* bu = (const float*)d_in[4];
    const float* Wp = (const float*)d_in[5];
    const float* bp = (const float*)d_in[6];
    const float* W1 = (const float*)d_in[7];
    const float* b1 = (const float*)d_in[8];
    const float* W2 = (const float*)d_in[9];
    const float* b2 = (const float*)d_in[10];
    const float* W3 = (const float*)d_in[11];
    const float* b3 = (const float*)d_in[12];
    const float* Wo = (const float*)d_in[13];
    const float* bo = (const float*)d_in[14];
    float* out = (float*)d_out;

    char* ws = (char*)d_ws;
    size_t p = 0;
    auto alloc = [&](size_t bytes) -> void* {
        void* r = ws + p;
        p += (bytes + 255) & ~(size_t)255;
        return r;
    };
    float* xA    = (float*)alloc((size_t)NN * H * 4);
    float* xB    = (float*)alloc((size_t)NN * H * 4);
    int*   cnt   = (int*)  alloc((size_t)NN * 4);
    int*   cursor= (int*)  alloc((size_t)NN * 4);
    int*   offs  = (int*)  alloc((size_t)(NN + 1) * 4);
    float* dinv  = (float*)alloc((size_t)NN * 4);
    int2*  epack = (int2*) alloc((size_t)NE * 8);
    int*   bsums = (int*)  alloc(128 * 4);

    const int NBLK = (NN + SCAN_CHUNK - 1) / SCAN_CHUNK;   // 98

    // graph structure (once per call, reused across 3 layers)
    k_init <<<(NN + 255) / 256, 256, 0, stream>>>(cnt, cursor, NN);
    k_count<<<(NE + 255) / 256, 256, 0, stream>>>(edst, cnt, NE);
    k_dinv <<<(NN + 255) / 256, 256, 0, stream>>>(cnt, dinv, NN);
    k_scan1<<<NBLK, SCAN_TPB, 0, stream>>>(cnt, offs, bsums, NN);
    k_scan2<<<1, 128, 0, stream>>>(bsums, NBLK, offs + NN);
    k_scan3<<<(NN + 255) / 256, 256, 0, stream>>>(offs, bsums, NN);
    k_fill <<<(NE + 255) / 256, 256, 0, stream>>>(esrc_in, edst, offs, cursor, dinv,
                                                  epack, NE);

    // input feature transforms -> xA
    k_gemm2<64, true>  <<<(NU + 127) / 128, 256, 0, stream>>>(user, Wu, bu, xA, NU, 0);
    k_gemm2<100, true> <<<(NP + 127) / 128, 256, 0, stream>>>(prod, Wp, bp, xA, NP, NU);

    // layer 1
    k_gemm2<H, false><<<(NN + 127) / 128, 256, 0, stream>>>(xA, W1, nullptr, xB, NN, 0);
    k_aggregate<<<NN / 4, 256, 0, stream>>>(xB, offs, epack, dinv, b1, xA);
    // layer 2
    k_gemm2<H, false><<<(NN + 127) / 128, 256, 0, stream>>>(xA, W2, nullptr, xB, NN, 0);
    k_aggregate<<<NN / 4, 256, 0, stream>>>(xB, offs, epack, dinv, b2, xA);
    // layer 3
    k_gemm2<H, false><<<(NN + 127) / 128, 256, 0, stream>>>(xA, W3, nullptr, xB, NN, 0);
    k_aggregate<<<NN / 4, 256, 0, stream>>>(xB, offs, epack, dinv, b3, xA);

    // output head
    k_out2<<<(NN + 127) / 128, 256, 0, stream>>>(xA, Wo, bo, out, NN);
}